// Round 7
// baseline (171.606 us; speedup 1.0000x reference)
//
#include <hip/hip_runtime.h>
#include <hip/hip_bf16.h>

#define B_   2
#define N_   2048
#define DM_  1024
#define H_   16
#define DK_  64
#define BLK_ 128
#define TB_  16

typedef unsigned short u16;
typedef unsigned int   u32;
using bf16x8 = __attribute__((ext_vector_type(8))) __bf16;
using f32x4  = __attribute__((ext_vector_type(4))) float;

#define OPAD 68    // Os rows of 64 fp32 (+4), epilogue overlay only

__device__ __forceinline__ u32 pack_bf16(float a, float b) {
  __hip_bfloat162 h = __float22bfloat162_rn(make_float2(a, b));
  u32 u; __builtin_memcpy(&u, &h, 4); return u;
}
__device__ __forceinline__ bf16x8 pack8(float4 f0, float4 f1, float sc) {
  u32 w[4];
  w[0] = pack_bf16(f0.x * sc, f0.y * sc); w[1] = pack_bf16(f0.z * sc, f0.w * sc);
  w[2] = pack_bf16(f1.x * sc, f1.y * sc); w[3] = pack_bf16(f1.z * sc, f1.w * sc);
  bf16x8 r; __builtin_memcpy(&r, w, 16); return r;
}

// ---------------- pre-pass 1: build per-(b,h,kblock) LDS IMAGES ----------------
// kimg: 128 rows x 64 bf16 (128B/row), chunk(16B) index XOR'd with (row&7).
// vimg: 64 d-rows x 128 bf16 (256B/row), chunk index XOR'd with (d&7).
// The attn kernel copies these verbatim with global_load_lds (linear dest), so
// the XOR swizzle lands in LDS for conflict-free b128 fragment reads (T2 +
// guide rule 21: swizzle BOTH sides -> pre-swizzle the global image).
__global__ void kv_convert(const float* __restrict__ k, const float* __restrict__ v,
                           u16* __restrict__ kimg, u16* __restrict__ vimg) {
  __shared__ u16 tile[BLK_][DK_ + 2];
  const int b = blockIdx.z, h = blockIdx.y, nb = blockIdx.x;
  const int t = threadIdx.x;
  const size_t obase = ((size_t)((b * H_ + h) * TB_ + nb)) * 8192;
  const int rr = t >> 4, cc = (t & 15) * 4;
  // K: convert + swizzle into block image
  {
    const float* kg = k + ((size_t)(b * N_ + nb * BLK_)) * DM_ + h * DK_;
    u16* kd = kimg + obase;
#pragma unroll
    for (int i = 0; i < 8; ++i) {
      const int r = rr + i * 16;
      const float4 f = *(const float4*)(kg + (size_t)r * DM_ + cc);
      const int so = ((((cc >> 3) ^ (r & 7)) << 3) | (cc & 4));
      *(uint2*)(kd + r * 64 + so) = make_uint2(pack_bf16(f.x, f.y), pack_bf16(f.z, f.w));
    }
  }
  // V: transpose via LDS, then swizzled block image (d-major, 128 n per row)
  {
    const float* vg = v + ((size_t)(b * N_ + nb * BLK_)) * DM_ + h * DK_;
#pragma unroll
    for (int i = 0; i < 8; ++i) {
      const int r = rr + i * 16;
      const float4 f = *(const float4*)(vg + (size_t)r * DM_ + cc);
      *(u32*)(&tile[r][cc])     = pack_bf16(f.x, f.y);
      *(u32*)(&tile[r][cc + 2]) = pack_bf16(f.z, f.w);
    }
    __syncthreads();
    // d = t&63: 64 distinct d per wave -> conflict-light column gather (R4 fix)
    const int d = t & 63, n0 = (t >> 6) * 32;
    u16* og = vimg + obase + d * 128;
#pragma unroll
    for (int j = 0; j < 32; j += 8) {
      u16 tmp[8];
#pragma unroll
      for (int x = 0; x < 8; ++x) tmp[x] = tile[n0 + j + x][d];
      uint4 w; __builtin_memcpy(&w, tmp, 16);
      const int chunk = (n0 + j) >> 3;
      *(uint4*)(og + ((chunk ^ (d & 7)) << 3)) = w;
    }
  }
}

// ---------------- pre-pass 2: mask + block_sparse -> flags {0,1,2} ----------------
__global__ void mask_flags_kernel(const int* __restrict__ mask, const int* __restrict__ bs,
                                  int* __restrict__ flags) {
  const int blk = blockIdx.x;
  const int kb = blk % TB_, qb = (blk / TB_) % TB_, b = blk / (TB_ * TB_);
  const int t = threadIdx.x;
  const int* mg = mask + (size_t)b * N_ * N_ + (size_t)(qb * BLK_) * N_ + kb * BLK_;
  int all1 = 1, any1 = 0;
  for (int i = t; i < BLK_ * BLK_ / 4; i += 256) {
    const int r = i >> 5, c = (i & 31) * 4;
    const int4 mv = *(const int4*)(mg + (size_t)r * N_ + c);
    all1 &= (mv.x != 0) & (mv.y != 0) & (mv.z != 0) & (mv.w != 0);
    any1 |= (mv.x != 0) | (mv.y != 0) | (mv.z != 0) | (mv.w != 0);
  }
  __shared__ int sAll[4], sAny[4];
  const int wv = t >> 6;
  const int wAll = __all(all1), wAny = __any(any1);
  if ((t & 63) == 0) { sAll[wv] = wAll; sAny[wv] = wAny; }
  __syncthreads();
  if (t == 0) {
    const int A = sAll[0] & sAll[1] & sAll[2] & sAll[3];
    const int O = sAny[0] | sAny[1] | sAny[2] | sAny[3];
    int f = 0;
    if (bs[qb * TB_ + kb] != 0 && O) f = A ? 1 : 2;
    flags[blk] = f;
  }
}

// async staging: each wave copies its 4KB slice of K and V images straight to LDS.
// No VGPR round-trip -> the R1-R3 spill failure mode is structurally impossible.
#define STAGE(blk_, bi_) do {                                                        \
    const u16* ksrc_ = kpl + (size_t)(blk_) * 8192 + wave * 2048 + lane * 8;         \
    const u16* vsrc_ = vpl + (size_t)(blk_) * 8192 + wave * 2048 + lane * 8;         \
    u16* kdst_ = lds + (bi_) * 8192 + wave * 2048;                                   \
    u16* vdst_ = lds + 16384 + (bi_) * 8192 + wave * 2048;                           \
    _Pragma("unroll")                                                                \
    for (int i2_ = 0; i2_ < 4; ++i2_) {                                              \
      __builtin_amdgcn_global_load_lds(                                              \
          (const __attribute__((address_space(1))) void*)(ksrc_ + i2_ * 512),        \
          (__attribute__((address_space(3))) void*)(kdst_ + i2_ * 512), 16, 0, 0);   \
      __builtin_amdgcn_global_load_lds(                                              \
          (const __attribute__((address_space(1))) void*)(vsrc_ + i2_ * 512),        \
          (__attribute__((address_space(3))) void*)(vdst_ + i2_ * 512), 16, 0, 0);   \
    }                                                                                \
  } while (0)

// ---------------- main: block-sparse flash attention ----------------
// WG = 128 q rows, grid 512 = (bh&31) + 32*qb (same-(b,h) WGs share XCD).
// Double-buffered global_load_lds staging from pre-swizzled images: ONE
// __syncthreads per iteration (its built-in vmcnt(0) drain is the producer
// handshake -- by then the loads issued at the top of the PREVIOUS iteration
// have had the whole compute phase to land, so the drain is free). Loads for
// block i+1 are issued right after the barrier; zero staging VALU, no VGPR
// round-trip. P never touches LDS: QK C-layout (lane holds tokens
// kt*16+quad*4+r for one q) remaps to the PV B-fragment (ks*32+quad*8+j) by a
// verified quad-exchange: per ks/nt, 4 cndmask-selects + 6 shfl_xor(16/32/48)
// + 8 cndmask. LDS = 2x(16KB K + 16KB V) = 64KB -> 2 WG/CU.
// (R6 used raw s_barrier + asm vmcnt -- semantically identical to
// __syncthreads; replaced with the intrinsic to rule out asm-interplay risk.)
__global__ __launch_bounds__(256, 2)
void attn_kernel(const float* __restrict__ q_, const u16* __restrict__ kimg,
                 const u16* __restrict__ vimg, const float* __restrict__ tau_p,
                 const int* __restrict__ mask, const int* __restrict__ flags,
                 float* __restrict__ o_out, float* __restrict__ l_out,
                 float* __restrict__ m_out) {
  __shared__ __align__(16) u16 lds[4 * 8192];   // [Ks0|Ks1|Vt0|Vt1] = 65536 B
  float* Os = (float*)lds;                      // 128 x OPAD fp32 epilogue overlay

  const int idx = blockIdx.x;
  const int bh = idx & 31, qb128 = idx >> 5;
  const int b = bh >> 4, h = bh & 15;
  const int t = threadIdx.x;
  const int wave = t >> 6, lane = t & 63, quad = lane >> 4, col = lane & 15;

  // active-kb bitmasks (uniform across the WG)
  const int* flg = flags + (b * TB_ + qb128) * TB_;
  u32 actmask = 0, mixmask = 0;
#pragma unroll
  for (int i = 0; i < TB_; ++i) {
    const int f = flg[i];
    actmask |= (f != 0) ? (1u << i) : 0u;
    mixmask |= (f == 2) ? (1u << i) : 0u;
  }

  const u16* kpl = kimg + (size_t)(b * H_ + h) * TB_ * 8192;
  const u16* vpl = vimg + (size_t)(b * H_ + h) * TB_ * 8192;

  u32 rem = actmask;
  int cur = -1;
  if (rem) { cur = (int)__builtin_ctz(rem); rem &= rem - 1; STAGE(cur, 0); }

  int qg[2];
  qg[0] = qb128 * BLK_ + wave * 32 + col;
  qg[1] = qg[0] + 16;

  // Q B-fragments from fp32 global (one-time; scale + log2e folded); hides the
  // first block's staging latency.
  const float qscale = tau_p[0] * 0.125f * 1.44269504f;
  bf16x8 bq[2][2];
#pragma unroll
  for (int nt = 0; nt < 2; ++nt) {
    const float* qr = q_ + ((size_t)(b * N_ + qg[nt])) * DM_ + h * DK_;
#pragma unroll
    for (int half = 0; half < 2; ++half) {
      const float4 f0 = *(const float4*)(qr + half * 32 + quad * 8);
      const float4 f1 = *(const float4*)(qr + half * 32 + quad * 8 + 4);
      bq[nt][half] = pack8(f0, f1, qscale);
    }
  }

  float m_run[2]  = {-INFINITY, -INFINITY};   // softmax base (lags true max <= THR)
  float m_true[2] = {-INFINITY, -INFINITY};   // true running max (for l/m outputs)
  float l_run[2] = {0.f, 0.f};
  f32x4 oacc[2][4];
#pragma unroll
  for (int nt = 0; nt < 2; ++nt)
#pragma unroll
    for (int mt = 0; mt < 4; ++mt) oacc[nt][mt] = (f32x4){0.f, 0.f, 0.f, 0.f};

  const int s8 = col & 7;                 // row&7 for K and V fragment rows
  const int a0o = (quad ^ s8) << 3;       // swizzled chunk offset (u16 units)
  const int q2 = quad >> 1;               // lane bit 5: selects kt parity

  int bufi = 0;
  while (cur >= 0) {
    // barrier (with built-in vmcnt(0) drain): publishes the buffer staged by the
    // loads issued one iteration ago; their latency was hidden under compute.
    __syncthreads();

    // issue next block's loads now -> they land during this iteration's compute.
    // buf[bufi^1] is dead: its readers finished before the barrier above.
    int nxt = -1;
    if (rem) { nxt = (int)__builtin_ctz(rem); rem &= rem - 1; STAGE(nxt, bufi ^ 1); }

    const int mix = (mixmask >> cur) & 1;
    const u16* KsB = lds + bufi * 8192;
    const u16* VtB = lds + 16384 + bufi * 8192;

    u32 pw[2][16];  // packed bf16 P pairs, [nt][kt*2+i] (all indices constant)

#pragma unroll
    for (int nt = 0; nt < 2; ++nt) {
      f32x4 st[8];
      __builtin_amdgcn_s_setprio(1);
#pragma unroll
      for (int kt = 0; kt < 8; ++kt) {
        const u16* krow = KsB + (kt * 16 + col) * 64;
        const bf16x8 a0 = *(const bf16x8*)(krow + a0o);
        const bf16x8 a1 = *(const bf16x8*)(krow + (a0o ^ 32));
        f32x4 c = (f32x4){0.f, 0.f, 0.f, 0.f};
        c = __builtin_amdgcn_mfma_f32_16x16x32_bf16(a0, bq[nt][0], c, 0, 0, 0);
        c = __builtin_amdgcn_mfma_f32_16x16x32_bf16(a1, bq[nt][1], c, 0, 0, 0);
        st[kt] = c;
      }
      __builtin_amdgcn_s_setprio(0);
      if (mix) {  // token mask (not taken with all-ones mask)
        const int* mg = mask + (size_t)b * N_ * N_ + (size_t)qg[nt] * N_ + cur * BLK_;
#pragma unroll
        for (int kt = 0; kt < 8; ++kt) {
          const int4 mv = *(const int4*)(mg + kt * 16 + quad * 4);
          if (!mv.x) st[kt][0] = -1e30f;
          if (!mv.y) st[kt][1] = -1e30f;
          if (!mv.z) st[kt][2] = -1e30f;
          if (!mv.w) st[kt][3] = -1e30f;
        }
      }
      float mx = -INFINITY;
#pragma unroll
      for (int kt = 0; kt < 8; ++kt)
        mx = fmaxf(mx, fmaxf(fmaxf(st[kt][0], st[kt][1]), fmaxf(st[kt][2], st[kt][3])));
      mx = fmaxf(mx, __shfl_xor(mx, 16, 64));
      mx = fmaxf(mx, __shfl_xor(mx, 32, 64));
      m_true[nt] = fmaxf(m_true[nt], mx);

      // T13 defer-rescale (THR=8 in log2 domain)
      const float mold = m_run[nt];
      float mnew = mold;
      if (!__all(mx <= mold + 8.f)) {
        mnew = fmaxf(mold, mx);
        const float alpha = __builtin_amdgcn_exp2f(mold - mnew);
        l_run[nt] *= alpha;
#pragma unroll
        for (int mt = 0; mt < 4; ++mt)
#pragma unroll
          for (int r = 0; r < 4; ++r) oacc[nt][mt][r] *= alpha;
        m_run[nt] = mnew;
      }

      float s = 0.f;
      if (!mix) {
#pragma unroll
        for (int kt = 0; kt < 8; ++kt) {
          const float p0 = __builtin_amdgcn_exp2f(st[kt][0] - mnew);
          const float p1 = __builtin_amdgcn_exp2f(st[kt][1] - mnew);
          const float p2 = __builtin_amdgcn_exp2f(st[kt][2] - mnew);
          const float p3 = __builtin_amdgcn_exp2f(st[kt][3] - mnew);
          s += (p0 + p1) + (p2 + p3);
          pw[nt][kt * 2 + 0] = pack_bf16(p0, p1);
          pw[nt][kt * 2 + 1] = pack_bf16(p2, p3);
        }
      } else {
#pragma unroll
        for (int kt = 0; kt < 8; ++kt) {
          const float p0 = st[kt][0] <= -1e29f ? 0.f : __builtin_amdgcn_exp2f(st[kt][0] - mnew);
          const float p1 = st[kt][1] <= -1e29f ? 0.f : __builtin_amdgcn_exp2f(st[kt][1] - mnew);
          const float p2 = st[kt][2] <= -1e29f ? 0.f : __builtin_amdgcn_exp2f(st[kt][2] - mnew);
          const float p3 = st[kt][3] <= -1e29f ? 0.f : __builtin_amdgcn_exp2f(st[kt][3] - mnew);
          s += (p0 + p1) + (p2 + p3);
          pw[nt][kt * 2 + 0] = pack_bf16(p0, p1);
          pw[nt][kt * 2 + 1] = pack_bf16(p2, p3);
        }
      }
      s += __shfl_xor(s, 16, 64);
      s += __shfl_xor(s, 32, 64);
      l_run[nt] += s;
    }

    // ---- O^T += V^T . P^T ; B-fragment built in-register via quad exchange ----
#pragma unroll
    for (int ks = 0; ks < 4; ++ks) {
      bf16x8 bfrag[2];
#pragma unroll
      for (int nt = 0; nt < 2; ++nt) {
        const u32 wA0 = pw[nt][4 * ks + 0], wA1 = pw[nt][4 * ks + 1];  // kt=2ks
        const u32 wB0 = pw[nt][4 * ks + 2], wB1 = pw[nt][4 * ks + 3];  // kt=2ks+1
        const u32 a0 = q2 ? wB0 : wA0;   // word0 of kt = 2ks+q2 (self quad-pair)
        const u32 a1 = q2 ? wB1 : wA1;
        const u32 b0 = q2 ? wA0 : wB0;   // word0 of kt = 2ks+!q2 (other pair)
        const u32 b1 = q2 ? wA1 : wB1;
        const u32 x16_0 = __shfl_xor(a0, 16, 64);
        const u32 x16_1 = __shfl_xor(a1, 16, 64);
        const u32 x32_0 = __shfl_xor(b0, 32, 64);
        const u32 x32_1 = __shfl_xor(b1, 32, 64);
        const u32 x48_0 = __shfl_xor(b0, 48, 64);
        const u32 x48_1 = __shfl_xor(b1, 48, 64);
        u32 wv[4];
        wv[0] = (quad & 2) ? ((quad & 1) ? x16_0 : x32_0) : ((quad & 1) ? x48_0 : a0);
        wv[1] = (quad & 2) ? ((quad & 1) ? x16_1 : x32_1) : ((quad & 1) ? x48_1 : a1);
        wv[2] = (quad & 2) ? ((quad & 1) ? a0 : x48_0) : ((quad & 1) ? x32_0 : x16_0);
        wv[3] = (quad & 2) ? ((quad & 1) ? a1 : x48_1) : ((quad & 1) ? x32_1 : x16_1);
        __builtin_memcpy(&bfrag[nt], wv, 16);
      }
      __builtin_amdgcn_s_setprio(1);
#pragma unroll
      for (int mt = 0; mt < 4; ++mt) {
        const bf16x8 av =
            *(const bf16x8*)(VtB + (mt * 16 + col) * 128 + (((ks * 4 + quad) ^ s8) << 3));
        oacc[0][mt] = __builtin_amdgcn_mfma_f32_16x16x32_bf16(av, bfrag[0], oacc[0][mt], 0, 0, 0);
        oacc[1][mt] = __builtin_amdgcn_mfma_f32_16x16x32_bf16(av, bfrag[1], oacc[1][mt], 0, 0, 0);
      }
      __builtin_amdgcn_s_setprio(0);
    }

    bufi ^= 1;
    cur = nxt;
  }

  // ---- epilogue: normalize, transpose O through LDS overlay, coalesced writes ----
  __syncthreads();  // all waves done with K/V buffers (and any stray loads drained)
#pragma unroll
  for (int nt = 0; nt < 2; ++nt) {
    const float inv = l_run[nt] > 0.f ? 1.f / l_run[nt] : 1.f;
    const int qloc = wave * 32 + nt * 16 + col;
#pragma unroll
    for (int mt = 0; mt < 4; ++mt) {
      float4 w = make_float4(oacc[nt][mt][0] * inv, oacc[nt][mt][1] * inv,
                             oacc[nt][mt][2] * inv, oacc[nt][mt][3] * inv);
      *(float4*)(Os + qloc * OPAD + mt * 16 + quad * 4) = w;
    }
  }
  __syncthreads();
  float* ob = o_out + ((size_t)(b * N_ + qb128 * BLK_)) * DM_ + h * DK_;
#pragma unroll
  for (int j = 0; j < 8; ++j) {
    const int i = t + 256 * j;
    const int r = i >> 4, c4 = (i & 15) * 4;
    const float4 w = *(const float4*)(Os + r * OPAD + c4);
    *(float4*)(ob + (size_t)r * DM_ + c4) = w;
  }
  if (quad == 0) {
#pragma unroll
    for (int nt = 0; nt < 2; ++nt) {
      const size_t oi = (size_t)(b * H_ + h) * N_ + qg[nt];
      const float lv = l_run[nt] > 0.f
          ? l_run[nt] * __builtin_amdgcn_exp2f(m_run[nt] - m_true[nt]) : 0.f;
      l_out[oi] = lv;
      m_out[oi] = l_run[nt] > 0.f ? m_true[nt] * 0.69314718056f : -INFINITY;
    }
  }
}

extern "C" void kernel_launch(void* const* d_in, const int* in_sizes, int n_in,
                              void* d_out, int out_size, void* d_ws, size_t ws_size,
                              hipStream_t stream) {
  const float* q   = (const float*)d_in[0];
  const float* k   = (const float*)d_in[1];
  const float* v   = (const float*)d_in[2];
  const float* tau = (const float*)d_in[3];
  const int* mask  = (const int*)d_in[4];
  const int* bs    = (const int*)d_in[5];
  float* out = (float*)d_out;

  const size_t plane = (size_t)B_ * H_ * N_ * DK_;  // == B*H*TB*8192
  u16* kimg = (u16*)d_ws;
  u16* vimg = kimg + plane;
  int* flags = (int*)(vimg + plane);

  kv_convert<<<dim3(TB_, H_, B_), 256, 0, stream>>>(k, v, kimg, vimg);
  mask_flags_kernel<<<B_ * TB_ * TB_, 256, 0, stream>>>(mask, bs, flags);

  float* o_out = out;
  float* l_out = out + (size_t)B_ * N_ * DM_;
  float* m_out = l_out + (size_t)B_ * H_ * N_;
  attn_kernel<<<dim3(TB_ * 32), 256, 0, stream>>>(q, kimg, vimg, tau, mask, flags,
                                                  o_out, l_out, m_out);
}

// Round 8
// 165.873 us; speedup vs baseline: 1.0346x; 1.0346x over previous
//
#include <hip/hip_runtime.h>
#include <hip/hip_bf16.h>

#define B_   2
#define N_   2048
#define DM_  1024
#define H_   16
#define DK_  64
#define BLK_ 128
#define TB_  16

typedef unsigned short u16;
typedef unsigned int   u32;
using bf16x8 = __attribute__((ext_vector_type(8))) __bf16;
using f32x4  = __attribute__((ext_vector_type(4))) float;

#define PPAD 136   // Ps rows of 128 bf16 (+8): b64 writes ~2-way, b128 reads min-phase
#define OPAD 68    // Os rows of 64 fp32 (+4), epilogue overlay only
#define QROWS 64   // q rows per WG: 4 waves x 16 q (tail quantum halved vs 128)

__device__ __forceinline__ u32 pack_bf16(float a, float b) {
  __hip_bfloat162 h = __float22bfloat162_rn(make_float2(a, b));
  u32 u; __builtin_memcpy(&u, &h, 4); return u;
}
__device__ __forceinline__ bf16x8 pack8(float4 f0, float4 f1, float sc) {
  u32 w[4];
  w[0] = pack_bf16(f0.x * sc, f0.y * sc); w[1] = pack_bf16(f0.z * sc, f0.w * sc);
  w[2] = pack_bf16(f1.x * sc, f1.y * sc); w[3] = pack_bf16(f1.z * sc, f1.w * sc);
  bf16x8 r; __builtin_memcpy(&r, w, 16); return r;
}

// ---------------- pre-pass 1: build per-(b,h,kblock) LDS IMAGES ----------------
// kimg: 128 rows x 64 bf16 (128B/row), 16B-chunk index XOR'd with (row&7).
// vimg: 64 d-rows x 128 bf16 (256B/row), chunk index XOR'd with (d&7).
// attn copies these verbatim with global_load_lds (linear dest) -> the XOR
// swizzle lands in LDS for conflict-free b128 fragment reads (measured R7:
// SQ_LDS_BANK_CONFLICT 4.45M -> 1.04M).
__global__ void kv_convert(const float* __restrict__ k, const float* __restrict__ v,
                           u16* __restrict__ kimg, u16* __restrict__ vimg) {
  __shared__ u16 tile[BLK_][DK_ + 2];
  const int b = blockIdx.z, h = blockIdx.y, nb = blockIdx.x;
  const int t = threadIdx.x;
  const size_t obase = ((size_t)((b * H_ + h) * TB_ + nb)) * 8192;
  const int rr = t >> 4, cc = (t & 15) * 4;
  // K: convert + swizzle into block image
  {
    const float* kg = k + ((size_t)(b * N_ + nb * BLK_)) * DM_ + h * DK_;
    u16* kd = kimg + obase;
#pragma unroll
    for (int i = 0; i < 8; ++i) {
      const int r = rr + i * 16;
      const float4 f = *(const float4*)(kg + (size_t)r * DM_ + cc);
      const int so = ((((cc >> 3) ^ (r & 7)) << 3) | (cc & 4));
      *(uint2*)(kd + r * 64 + so) = make_uint2(pack_bf16(f.x, f.y), pack_bf16(f.z, f.w));
    }
  }
  // V: transpose via LDS, then swizzled block image (d-major, 128 n per row)
  {
    const float* vg = v + ((size_t)(b * N_ + nb * BLK_)) * DM_ + h * DK_;
#pragma unroll
    for (int i = 0; i < 8; ++i) {
      const int r = rr + i * 16;
      const float4 f = *(const float4*)(vg + (size_t)r * DM_ + cc);
      *(u32*)(&tile[r][cc])     = pack_bf16(f.x, f.y);
      *(u32*)(&tile[r][cc + 2]) = pack_bf16(f.z, f.w);
    }
    __syncthreads();
    // d = t&63: 64 distinct d per wave -> conflict-light column gather (R4 fix)
    const int d = t & 63, n0 = (t >> 6) * 32;
    u16* og = vimg + obase + d * 128;
#pragma unroll
    for (int j = 0; j < 32; j += 8) {
      u16 tmp[8];
#pragma unroll
      for (int x = 0; x < 8; ++x) tmp[x] = tile[n0 + j + x][d];
      uint4 w; __builtin_memcpy(&w, tmp, 16);
      const int chunk = (n0 + j) >> 3;
      *(uint4*)(og + ((chunk ^ (d & 7)) << 3)) = w;
    }
  }
}

// ---------------- pre-pass 2: mask + block_sparse -> flags {0,1,2} ----------------
__global__ void mask_flags_kernel(const int* __restrict__ mask, const int* __restrict__ bs,
                                  int* __restrict__ flags) {
  const int blk = blockIdx.x;
  const int kb = blk % TB_, qb = (blk / TB_) % TB_, b = blk / (TB_ * TB_);
  const int t = threadIdx.x;
  const int* mg = mask + (size_t)b * N_ * N_ + (size_t)(qb * BLK_) * N_ + kb * BLK_;
  int all1 = 1, any1 = 0;
  for (int i = t; i < BLK_ * BLK_ / 4; i += 256) {
    const int r = i >> 5, c = (i & 31) * 4;
    const int4 mv = *(const int4*)(mg + (size_t)r * N_ + c);
    all1 &= (mv.x != 0) & (mv.y != 0) & (mv.z != 0) & (mv.w != 0);
    any1 |= (mv.x != 0) | (mv.y != 0) | (mv.z != 0) | (mv.w != 0);
  }
  __shared__ int sAll[4], sAny[4];
  const int wv = t >> 6;
  const int wAll = __all(all1), wAny = __any(any1);
  if ((t & 63) == 0) { sAll[wv] = wAll; sAny[wv] = wAny; }
  __syncthreads();
  if (t == 0) {
    const int A = sAll[0] & sAll[1] & sAll[2] & sAll[3];
    const int O = sAny[0] | sAny[1] | sAny[2] | sAny[3];
    int f = 0;
    if (bs[qb * TB_ + kb] != 0 && O) f = A ? 1 : 2;
    flags[blk] = f;
  }
}

// async staging: each wave copies its 4KB slice of the K and V images to LDS.
// Zero staging VALU, no VGPR round-trip (R1-R3 spill mode impossible).
#define STAGE(blk_) do {                                                             \
    const u16* ksrc_ = kpl + (size_t)(blk_) * 8192 + wave * 2048 + lane * 8;         \
    const u16* vsrc_ = vpl + (size_t)(blk_) * 8192 + wave * 2048 + lane * 8;         \
    u16* kdst_ = lds + wave * 2048;                                                  \
    u16* vdst_ = lds + 8192 + wave * 2048;                                           \
    _Pragma("unroll")                                                                \
    for (int i2_ = 0; i2_ < 4; ++i2_) {                                              \
      __builtin_amdgcn_global_load_lds(                                              \
          (const __attribute__((address_space(1))) void*)(ksrc_ + i2_ * 512),        \
          (__attribute__((address_space(3))) void*)(kdst_ + i2_ * 512), 16, 0, 0);   \
      __builtin_amdgcn_global_load_lds(                                              \
          (const __attribute__((address_space(1))) void*)(vsrc_ + i2_ * 512),        \
          (__attribute__((address_space(3))) void*)(vdst_ + i2_ * 512), 16, 0, 0);   \
    }                                                                                \
  } while (0)

// ---------------- main: block-sparse flash attention (split-Q + async stage) ----------------
// WG = 64 q rows (4 waves x 16 q), grid 1024 = (bh&31) + 32*qb64 (same-(b,h) WGs
// share XCD). Single-buffered K/V staged by global_load_lds from the pre-swizzled
// images (zero staging VALU; conflicts stay low, R7-measured); 2 barriers/iter.
// LDS = 16K(K) + 16K(V) + 17.4K(Ps) = 50176 B -> 3 WG/CU CAPACITY against a
// 4 WG/CU-average grid: the binomial(16,1/2) work tail gets dynamically packed
// (R5's occupancy gain) while the staging duplication it costs is now nearly
// free (R7's staging). P goes through wave-private LDS rows -- R7 proved the
// in-register shuffle exchange is a net loss (VALUBusy 24->30%, +6us); R4's Ps
// round-trip is the cheap redistribution.
__global__ __launch_bounds__(256, 3)
void attn_kernel(const float* __restrict__ q_, const u16* __restrict__ kimg,
                 const u16* __restrict__ vimg, const float* __restrict__ tau_p,
                 const int* __restrict__ mask, const int* __restrict__ flags,
                 float* __restrict__ o_out, float* __restrict__ l_out,
                 float* __restrict__ m_out) {
  __shared__ __align__(16) u16 lds[8192 + 8192 + QROWS * PPAD];   // 50176 B
  u16* Ps  = lds + 16384;                 // 64 x PPAD (wave-private 16-row stripes)
  float* Os = (float*)lds;                // 64 x OPAD fp32 epilogue overlay (17408 B)

  const int idx = blockIdx.x;
  const int bh = idx & 31, qb64 = idx >> 5;
  const int b = bh >> 4, h = bh & 15;
  const int qb128 = qb64 >> 1;
  const int t = threadIdx.x;
  const int wave = t >> 6, lane = t & 63, quad = lane >> 4, col = lane & 15;

  // active-kb bitmasks (uniform across the WG)
  const int* flg = flags + (b * TB_ + qb128) * TB_;
  u32 actmask = 0, mixmask = 0;
#pragma unroll
  for (int i = 0; i < TB_; ++i) {
    const int f = flg[i];
    actmask |= (f != 0) ? (1u << i) : 0u;
    mixmask |= (f == 2) ? (1u << i) : 0u;
  }

  const u16* kpl = kimg + (size_t)(b * H_ + h) * TB_ * 8192;
  const u16* vpl = vimg + (size_t)(b * H_ + h) * TB_ * 8192;

  const int qg = qb64 * QROWS + wave * 16 + col;   // this lane's q row

  // Q B-fragment from fp32 global (one-time; scale + log2e folded)
  const float qscale = tau_p[0] * 0.125f * 1.44269504f;
  bf16x8 bq[2];
  {
    const float* qr = q_ + ((size_t)(b * N_ + qg)) * DM_ + h * DK_;
#pragma unroll
    for (int half = 0; half < 2; ++half) {
      const float4 f0 = *(const float4*)(qr + half * 32 + quad * 8);
      const float4 f1 = *(const float4*)(qr + half * 32 + quad * 8 + 4);
      bq[half] = pack8(f0, f1, qscale);
    }
  }

  float m_run  = -INFINITY;   // softmax base (lags true max <= THR)
  float m_true = -INFINITY;   // true running max (for l/m outputs)
  float l_run  = 0.f;
  f32x4 oacc[4];
#pragma unroll
  for (int mt = 0; mt < 4; ++mt) oacc[mt] = (f32x4){0.f, 0.f, 0.f, 0.f};

  const int s8 = col & 7;                 // (fragment row) & 7 for K and V reads
  const int a0o = (quad ^ s8) << 3;       // swizzled 16B-chunk offset (u16 units)
  const int qloc = wave * 16 + col;       // Ps row

  u32 rem = actmask;
  while (rem) {
    const int cur = (int)__builtin_ctz(rem);
    rem &= rem - 1;
    const int mix = (mixmask >> cur) & 1;

    __syncthreads();          // previous iter's K/V fragment reads complete
    STAGE(cur);               // issue async copies; no VALU, no registers
    __syncthreads();          // vmcnt drain publishes the staged buffers

    // ---- S^T = K.Q^T (one 16-q tile per wave), swizzled K reads ----
    f32x4 st[8];
    __builtin_amdgcn_s_setprio(1);
#pragma unroll
    for (int kt = 0; kt < 8; ++kt) {
      const u16* krow = lds + (kt * 16 + col) * 64;
      const bf16x8 a0 = *(const bf16x8*)(krow + a0o);
      const bf16x8 a1 = *(const bf16x8*)(krow + (a0o ^ 32));
      f32x4 c = (f32x4){0.f, 0.f, 0.f, 0.f};
      c = __builtin_amdgcn_mfma_f32_16x16x32_bf16(a0, bq[0], c, 0, 0, 0);
      c = __builtin_amdgcn_mfma_f32_16x16x32_bf16(a1, bq[1], c, 0, 0, 0);
      st[kt] = c;
    }
    __builtin_amdgcn_s_setprio(0);
    if (mix) {  // token mask (not taken with all-ones mask)
      const int* mg = mask + (size_t)b * N_ * N_ + (size_t)qg * N_ + cur * BLK_;
#pragma unroll
      for (int kt = 0; kt < 8; ++kt) {
        const int4 mv = *(const int4*)(mg + kt * 16 + quad * 4);
        if (!mv.x) st[kt][0] = -1e30f;
        if (!mv.y) st[kt][1] = -1e30f;
        if (!mv.z) st[kt][2] = -1e30f;
        if (!mv.w) st[kt][3] = -1e30f;
      }
    }
    float mx = -INFINITY;
#pragma unroll
    for (int kt = 0; kt < 8; ++kt)
      mx = fmaxf(mx, fmaxf(fmaxf(st[kt][0], st[kt][1]), fmaxf(st[kt][2], st[kt][3])));
    mx = fmaxf(mx, __shfl_xor(mx, 16, 64));
    mx = fmaxf(mx, __shfl_xor(mx, 32, 64));
    m_true = fmaxf(m_true, mx);

    // T13 defer-rescale: skip the O/l rescale unless a row grew past THR=8 (log2).
    const float mold = m_run;
    float mnew = mold;
    if (!__all(mx <= mold + 8.f)) {
      mnew = fmaxf(mold, mx);
      const float alpha = __builtin_amdgcn_exp2f(mold - mnew);
      l_run *= alpha;
#pragma unroll
      for (int mt = 0; mt < 4; ++mt)
#pragma unroll
        for (int r = 0; r < 4; ++r) oacc[mt][r] *= alpha;
      m_run = mnew;
    }

    float s = 0.f;
    if (!mix) {
#pragma unroll
      for (int kt = 0; kt < 8; ++kt) {
        const float p0 = __builtin_amdgcn_exp2f(st[kt][0] - mnew);
        const float p1 = __builtin_amdgcn_exp2f(st[kt][1] - mnew);
        const float p2 = __builtin_amdgcn_exp2f(st[kt][2] - mnew);
        const float p3 = __builtin_amdgcn_exp2f(st[kt][3] - mnew);
        s += (p0 + p1) + (p2 + p3);
        *(uint2*)(Ps + qloc * PPAD + kt * 16 + quad * 4) =
            make_uint2(pack_bf16(p0, p1), pack_bf16(p2, p3));
      }
    } else {
#pragma unroll
      for (int kt = 0; kt < 8; ++kt) {
        const float p0 = st[kt][0] <= -1e29f ? 0.f : __builtin_amdgcn_exp2f(st[kt][0] - mnew);
        const float p1 = st[kt][1] <= -1e29f ? 0.f : __builtin_amdgcn_exp2f(st[kt][1] - mnew);
        const float p2 = st[kt][2] <= -1e29f ? 0.f : __builtin_amdgcn_exp2f(st[kt][2] - mnew);
        const float p3 = st[kt][3] <= -1e29f ? 0.f : __builtin_amdgcn_exp2f(st[kt][3] - mnew);
        s += (p0 + p1) + (p2 + p3);
        *(uint2*)(Ps + qloc * PPAD + kt * 16 + quad * 4) =
            make_uint2(pack_bf16(p0, p1), pack_bf16(p2, p3));
      }
    }
    s += __shfl_xor(s, 16, 64);
    s += __shfl_xor(s, 32, 64);
    l_run += s;

    // ---- O^T += V^T . P^T ; P from wave-private LDS, swizzled V reads ----
    __builtin_amdgcn_s_setprio(1);
#pragma unroll
    for (int ks = 0; ks < 4; ++ks) {
      const bf16x8 bfrag = *(const bf16x8*)(Ps + qloc * PPAD + ks * 32 + quad * 8);
#pragma unroll
      for (int mt = 0; mt < 4; ++mt) {
        const bf16x8 av =
            *(const bf16x8*)(lds + 8192 + (mt * 16 + col) * 128 + (((ks * 4 + quad) ^ s8) << 3));
        oacc[mt] = __builtin_amdgcn_mfma_f32_16x16x32_bf16(av, bfrag, oacc[mt], 0, 0, 0);
      }
    }
    __builtin_amdgcn_s_setprio(0);
  }

  // ---- epilogue: normalize, transpose O through LDS overlay, coalesced writes ----
  __syncthreads();  // all waves done with K/V/Ps before Os overlay
  {
    const float inv = l_run > 0.f ? 1.f / l_run : 1.f;
#pragma unroll
    for (int mt = 0; mt < 4; ++mt) {
      float4 w = make_float4(oacc[mt][0] * inv, oacc[mt][1] * inv,
                             oacc[mt][2] * inv, oacc[mt][3] * inv);
      *(float4*)(Os + qloc * OPAD + mt * 16 + quad * 4) = w;
    }
  }
  __syncthreads();
  float* ob = o_out + ((size_t)(b * N_ + qb64 * QROWS)) * DM_ + h * DK_;
#pragma unroll
  for (int j = 0; j < 4; ++j) {
    const int i = t + 256 * j;
    const int r = i >> 4, c4 = (i & 15) * 4;
    const float4 w = *(const float4*)(Os + r * OPAD + c4);
    *(float4*)(ob + (size_t)r * DM_ + c4) = w;
  }
  if (quad == 0) {
    const size_t oi = (size_t)(b * H_ + h) * N_ + qg;
    const float lv = l_run > 0.f
        ? l_run * __builtin_amdgcn_exp2f(m_run - m_true) : 0.f;
    l_out[oi] = lv;
    m_out[oi] = l_run > 0.f ? m_true * 0.69314718056f : -INFINITY;
  }
}

extern "C" void kernel_launch(void* const* d_in, const int* in_sizes, int n_in,
                              void* d_out, int out_size, void* d_ws, size_t ws_size,
                              hipStream_t stream) {
  const float* q   = (const float*)d_in[0];
  const float* k   = (const float*)d_in[1];
  const float* v   = (const float*)d_in[2];
  const float* tau = (const float*)d_in[3];
  const int* mask  = (const int*)d_in[4];
  const int* bs    = (const int*)d_in[5];
  float* out = (float*)d_out;

  const size_t plane = (size_t)B_ * H_ * N_ * DK_;  // == B*H*TB*8192
  u16* kimg = (u16*)d_ws;
  u16* vimg = kimg + plane;
  int* flags = (int*)(vimg + plane);

  kv_convert<<<dim3(TB_, H_, B_), 256, 0, stream>>>(k, v, kimg, vimg);
  mask_flags_kernel<<<B_ * TB_ * TB_, 256, 0, stream>>>(mask, bs, flags);

  float* o_out = out;
  float* l_out = out + (size_t)B_ * N_ * DM_;
  float* m_out = l_out + (size_t)B_ * H_ * N_;
  attn_kernel<<<dim3((N_ / QROWS) * 32), 256, 0, stream>>>(q, kimg, vimg, tau, mask, flags,
                                                           o_out, l_out, m_out);
}

// Round 9
// 159.054 us; speedup vs baseline: 1.0789x; 1.0429x over previous
//
#include <hip/hip_runtime.h>
#include <hip/hip_bf16.h>

#define B_   2
#define N_   2048
#define DM_  1024
#define H_   16
#define DK_  64
#define BLK_ 128
#define TB_  16

typedef unsigned short u16;
typedef unsigned int   u32;
using bf16x8 = __attribute__((ext_vector_type(8))) __bf16;
using f32x4  = __attribute__((ext_vector_type(4))) float;

#define PPAD 136   // Ps rows of 128 bf16 (+8)
#define OPAD 68    // Os rows of 64 fp32 (+4), epilogue overlay only

__device__ __forceinline__ u32 pack_bf16(float a, float b) {
  __hip_bfloat162 h = __float22bfloat162_rn(make_float2(a, b));
  u32 u; __builtin_memcpy(&u, &h, 4); return u;
}
__device__ __forceinline__ bf16x8 pack8(float4 f0, float4 f1, float sc) {
  u32 w[4];
  w[0] = pack_bf16(f0.x * sc, f0.y * sc); w[1] = pack_bf16(f0.z * sc, f0.w * sc);
  w[2] = pack_bf16(f1.x * sc, f1.y * sc); w[3] = pack_bf16(f1.z * sc, f1.w * sc);
  bf16x8 r; __builtin_memcpy(&r, w, 16); return r;
}

// ---------------- fused pre-pass: KV images (blocks 0..511) + flags (512..1023) ----------------
// kimg: 128 rows x 64 bf16 (128B/row), 16B-chunk index XOR'd with (row&7).
// vimg: 64 d-rows x 128 bf16 (256B/row), chunk index XOR'd with (d&7).
// attn copies these verbatim with global_load_lds (linear dest) -> swizzle lands
// in LDS for conflict-free b128 fragment reads (R7/R8-measured: 4.45M -> ~1.0M).
// Fusion rationale: the two pre-passes are independent; one launch removes a
// serial kernel boundary and overlaps their HBM traffic.
__global__ void prepass_kernel(const float* __restrict__ k, const float* __restrict__ v,
                               const int* __restrict__ mask, const int* __restrict__ bs,
                               u16* __restrict__ kimg, u16* __restrict__ vimg,
                               int* __restrict__ flags) {
  __shared__ u16 tile[BLK_][DK_ + 2];
  __shared__ int sAll[4], sAny[4];
  const int blk0 = blockIdx.x;
  const int t = threadIdx.x;
  if (blk0 < 512) {
    // ---- KV image build ----
    const int nb = blk0 & 15, h = (blk0 >> 4) & 15, b = blk0 >> 8;
    const size_t obase = ((size_t)((b * H_ + h) * TB_ + nb)) * 8192;
    const int rr = t >> 4, cc = (t & 15) * 4;
    {
      const float* kg = k + ((size_t)(b * N_ + nb * BLK_)) * DM_ + h * DK_;
      u16* kd = kimg + obase;
#pragma unroll
      for (int i = 0; i < 8; ++i) {
        const int r = rr + i * 16;
        const float4 f = *(const float4*)(kg + (size_t)r * DM_ + cc);
        const int so = ((((cc >> 3) ^ (r & 7)) << 3) | (cc & 4));
        *(uint2*)(kd + r * 64 + so) = make_uint2(pack_bf16(f.x, f.y), pack_bf16(f.z, f.w));
      }
    }
    {
      const float* vg = v + ((size_t)(b * N_ + nb * BLK_)) * DM_ + h * DK_;
#pragma unroll
      for (int i = 0; i < 8; ++i) {
        const int r = rr + i * 16;
        const float4 f = *(const float4*)(vg + (size_t)r * DM_ + cc);
        *(u32*)(&tile[r][cc])     = pack_bf16(f.x, f.y);
        *(u32*)(&tile[r][cc + 2]) = pack_bf16(f.z, f.w);
      }
      __syncthreads();
      // d = t&63: 64 distinct d per wave -> conflict-light column gather (R4 fix)
      const int d = t & 63, n0 = (t >> 6) * 32;
      u16* og = vimg + obase + d * 128;
#pragma unroll
      for (int j = 0; j < 32; j += 8) {
        u16 tmp[8];
#pragma unroll
        for (int x = 0; x < 8; ++x) tmp[x] = tile[n0 + j + x][d];
        uint4 w; __builtin_memcpy(&w, tmp, 16);
        const int chunk = (n0 + j) >> 3;
        *(uint4*)(og + ((chunk ^ (d & 7)) << 3)) = w;
      }
    }
  } else {
    // ---- mask + block_sparse -> flags {0,1,2} ----
    const int blk = blk0 - 512;
    const int kb = blk % TB_, qb = (blk / TB_) % TB_, b = blk / (TB_ * TB_);
    const int* mg = mask + (size_t)b * N_ * N_ + (size_t)(qb * BLK_) * N_ + kb * BLK_;
    int all1 = 1, any1 = 0;
    for (int i = t; i < BLK_ * BLK_ / 4; i += 256) {
      const int r = i >> 5, c = (i & 31) * 4;
      const int4 mv = *(const int4*)(mg + (size_t)r * N_ + c);
      all1 &= (mv.x != 0) & (mv.y != 0) & (mv.z != 0) & (mv.w != 0);
      any1 |= (mv.x != 0) | (mv.y != 0) | (mv.z != 0) | (mv.w != 0);
    }
    const int wv = t >> 6;
    const int wAll = __all(all1), wAny = __any(any1);
    if ((t & 63) == 0) { sAll[wv] = wAll; sAny[wv] = wAny; }
    __syncthreads();
    if (t == 0) {
      const int A = sAll[0] & sAll[1] & sAll[2] & sAll[3];
      const int O = sAny[0] | sAny[1] | sAny[2] | sAny[3];
      int f = 0;
      if (bs[qb * TB_ + kb] != 0 && O) f = A ? 1 : 2;
      flags[blk] = f;
    }
  }
}

// async staging: each wave copies its 4KB slice of the K and V images to LDS.
// Zero staging VALU, no VGPR round-trip (R1-R3 spill mode impossible).
#define STAGE(blk_) do {                                                             \
    const u16* ksrc_ = kpl + (size_t)(blk_) * 8192 + wave * 2048 + lane * 8;         \
    const u16* vsrc_ = vpl + (size_t)(blk_) * 8192 + wave * 2048 + lane * 8;         \
    u16* kdst_ = lds + wave * 2048;                                                  \
    u16* vdst_ = lds + 8192 + wave * 2048;                                           \
    _Pragma("unroll")                                                                \
    for (int i2_ = 0; i2_ < 4; ++i2_) {                                              \
      __builtin_amdgcn_global_load_lds(                                              \
          (const __attribute__((address_space(1))) void*)(ksrc_ + i2_ * 512),        \
          (__attribute__((address_space(3))) void*)(kdst_ + i2_ * 512), 16, 0, 0);   \
      __builtin_amdgcn_global_load_lds(                                              \
          (const __attribute__((address_space(1))) void*)(vsrc_ + i2_ * 512),        \
          (__attribute__((address_space(3))) void*)(vdst_ + i2_ * 512), 16, 0, 0);   \
    }                                                                                \
  } while (0)

// ---------------- main: block-sparse flash attention ----------------
// R4 structure EXACTLY (the best-measured variant: 128q WG, grid 512 = (bh&31) +
// 32*qb for XCD-local K/V L2 reuse, per-nt sequential QK+softmax, Ps wave-private
// LDS round-trip, 2 barriers/iter, setprio, defer-rescale) with only its residual
// waste removed: staging now async global_load_lds from the pre-swizzled images
// (zero staging VALU / regs -- R8-proven), and K/V fragment reads use the XOR
// swizzle (kills the ~3.4M pad-layout bank conflicts -- R7-proven). Measured
// context: occupancy/split-Q variants (R5/R8) and shuffle-P (R7) all LOST to this
// structure; the remaining levers were staging VALU + K/V conflicts, both now 0.
// LDS = 16K(K) + 16K(V) + 34.8K(Ps) = 67584 B -> 2 WG/CU (same residency as R4).
__global__ __launch_bounds__(256, 2)
void attn_kernel(const float* __restrict__ q_, const u16* __restrict__ kimg,
                 const u16* __restrict__ vimg, const float* __restrict__ tau_p,
                 const int* __restrict__ mask, const int* __restrict__ flags,
                 float* __restrict__ o_out, float* __restrict__ l_out,
                 float* __restrict__ m_out) {
  __shared__ __align__(16) u16 lds[8192 + 8192 + BLK_ * PPAD];   // 67584 B
  u16* Ps  = lds + 16384;                 // 128 x PPAD (wave-private 32-row stripes)
  float* Os = (float*)lds;                // 128 x OPAD fp32 epilogue overlay (34816 B)

  const int idx = blockIdx.x;
  const int bh = idx & 31, qb128 = idx >> 5;
  const int b = bh >> 4, h = bh & 15;
  const int t = threadIdx.x;
  const int wave = t >> 6, lane = t & 63, quad = lane >> 4, col = lane & 15;

  // active-kb bitmasks (uniform across the WG)
  const int* flg = flags + (b * TB_ + qb128) * TB_;
  u32 actmask = 0, mixmask = 0;
#pragma unroll
  for (int i = 0; i < TB_; ++i) {
    const int f = flg[i];
    actmask |= (f != 0) ? (1u << i) : 0u;
    mixmask |= (f == 2) ? (1u << i) : 0u;
  }

  const u16* kpl = kimg + (size_t)(b * H_ + h) * TB_ * 8192;
  const u16* vpl = vimg + (size_t)(b * H_ + h) * TB_ * 8192;

  int qg[2];
  qg[0] = qb128 * BLK_ + wave * 32 + col;
  qg[1] = qg[0] + 16;

  // Q B-fragments from fp32 global (one-time; scale + log2e folded)
  const float qscale = tau_p[0] * 0.125f * 1.44269504f;
  bf16x8 bq[2][2];
#pragma unroll
  for (int nt = 0; nt < 2; ++nt) {
    const float* qr = q_ + ((size_t)(b * N_ + qg[nt])) * DM_ + h * DK_;
#pragma unroll
    for (int half = 0; half < 2; ++half) {
      const float4 f0 = *(const float4*)(qr + half * 32 + quad * 8);
      const float4 f1 = *(const float4*)(qr + half * 32 + quad * 8 + 4);
      bq[nt][half] = pack8(f0, f1, qscale);
    }
  }

  float m_run[2]  = {-INFINITY, -INFINITY};   // softmax base (lags true max <= THR)
  float m_true[2] = {-INFINITY, -INFINITY};   // true running max (for l/m outputs)
  float l_run[2] = {0.f, 0.f};
  f32x4 oacc[2][4];
#pragma unroll
  for (int nt = 0; nt < 2; ++nt)
#pragma unroll
    for (int mt = 0; mt < 4; ++mt) oacc[nt][mt] = (f32x4){0.f, 0.f, 0.f, 0.f};

  const int s8 = col & 7;                 // (fragment row) & 7 for K and V reads
  const int a0o = (quad ^ s8) << 3;       // swizzled 16B-chunk offset (u16 units)

  u32 rem = actmask;
  while (rem) {
    const int cur = (int)__builtin_ctz(rem);
    rem &= rem - 1;
    const int mix = (mixmask >> cur) & 1;

    __syncthreads();          // previous iter's K/V fragment reads complete
    STAGE(cur);               // issue async copies; no VALU, no registers
    __syncthreads();          // vmcnt drain publishes the staged buffers

    // ---- per q-tile: S^T = K.Q^T (swizzled K reads), softmax, P -> LDS ----
#pragma unroll
    for (int nt = 0; nt < 2; ++nt) {
      f32x4 st[8];
      __builtin_amdgcn_s_setprio(1);
#pragma unroll
      for (int kt = 0; kt < 8; ++kt) {
        const u16* krow = lds + (kt * 16 + col) * 64;
        const bf16x8 a0 = *(const bf16x8*)(krow + a0o);
        const bf16x8 a1 = *(const bf16x8*)(krow + (a0o ^ 32));
        f32x4 c = (f32x4){0.f, 0.f, 0.f, 0.f};
        c = __builtin_amdgcn_mfma_f32_16x16x32_bf16(a0, bq[nt][0], c, 0, 0, 0);
        c = __builtin_amdgcn_mfma_f32_16x16x32_bf16(a1, bq[nt][1], c, 0, 0, 0);
        st[kt] = c;
      }
      __builtin_amdgcn_s_setprio(0);
      if (mix) {  // token mask (not taken with all-ones mask)
        const int* mg = mask + (size_t)b * N_ * N_ + (size_t)qg[nt] * N_ + cur * BLK_;
#pragma unroll
        for (int kt = 0; kt < 8; ++kt) {
          const int4 mv = *(const int4*)(mg + kt * 16 + quad * 4);
          if (!mv.x) st[kt][0] = -1e30f;
          if (!mv.y) st[kt][1] = -1e30f;
          if (!mv.z) st[kt][2] = -1e30f;
          if (!mv.w) st[kt][3] = -1e30f;
        }
      }
      float mx = -INFINITY;
#pragma unroll
      for (int kt = 0; kt < 8; ++kt)
        mx = fmaxf(mx, fmaxf(fmaxf(st[kt][0], st[kt][1]), fmaxf(st[kt][2], st[kt][3])));
      mx = fmaxf(mx, __shfl_xor(mx, 16, 64));
      mx = fmaxf(mx, __shfl_xor(mx, 32, 64));
      m_true[nt] = fmaxf(m_true[nt], mx);

      // T13 defer-rescale: skip the O/l rescale unless a row grew past THR=8 (log2).
      const float mold = m_run[nt];
      float mnew = mold;
      if (!__all(mx <= mold + 8.f)) {
        mnew = fmaxf(mold, mx);
        const float alpha = __builtin_amdgcn_exp2f(mold - mnew);
        l_run[nt] *= alpha;
#pragma unroll
        for (int mt = 0; mt < 4; ++mt)
#pragma unroll
          for (int r = 0; r < 4; ++r) oacc[nt][mt][r] *= alpha;
        m_run[nt] = mnew;
      }

      const int qloc = wave * 32 + nt * 16 + col;
      float s = 0.f;
      if (!mix) {
#pragma unroll
        for (int kt = 0; kt < 8; ++kt) {
          const float p0 = __builtin_amdgcn_exp2f(st[kt][0] - mnew);
          const float p1 = __builtin_amdgcn_exp2f(st[kt][1] - mnew);
          const float p2 = __builtin_amdgcn_exp2f(st[kt][2] - mnew);
          const float p3 = __builtin_amdgcn_exp2f(st[kt][3] - mnew);
          s += (p0 + p1) + (p2 + p3);
          *(uint2*)(Ps + qloc * PPAD + kt * 16 + quad * 4) =
              make_uint2(pack_bf16(p0, p1), pack_bf16(p2, p3));
        }
      } else {
#pragma unroll
        for (int kt = 0; kt < 8; ++kt) {
          const float p0 = st[kt][0] <= -1e29f ? 0.f : __builtin_amdgcn_exp2f(st[kt][0] - mnew);
          const float p1 = st[kt][1] <= -1e29f ? 0.f : __builtin_amdgcn_exp2f(st[kt][1] - mnew);
          const float p2 = st[kt][2] <= -1e29f ? 0.f : __builtin_amdgcn_exp2f(st[kt][2] - mnew);
          const float p3 = st[kt][3] <= -1e29f ? 0.f : __builtin_amdgcn_exp2f(st[kt][3] - mnew);
          s += (p0 + p1) + (p2 + p3);
          *(uint2*)(Ps + qloc * PPAD + kt * 16 + quad * 4) =
              make_uint2(pack_bf16(p0, p1), pack_bf16(p2, p3));
        }
      }
      s += __shfl_xor(s, 16, 64);
      s += __shfl_xor(s, 32, 64);
      l_run[nt] += s;
    }

    // ---- O^T += V^T . P^T ; P from wave-private LDS, swizzled V reads ----
    __builtin_amdgcn_s_setprio(1);
#pragma unroll
    for (int ks = 0; ks < 4; ++ks) {
      bf16x8 bfrag[2];
#pragma unroll
      for (int nt = 0; nt < 2; ++nt)
        bfrag[nt] = *(const bf16x8*)(Ps + (wave * 32 + nt * 16 + col) * PPAD + ks * 32 + quad * 8);
#pragma unroll
      for (int mt = 0; mt < 4; ++mt) {
        const bf16x8 av =
            *(const bf16x8*)(lds + 8192 + (mt * 16 + col) * 128 + (((ks * 4 + quad) ^ s8) << 3));
        oacc[0][mt] = __builtin_amdgcn_mfma_f32_16x16x32_bf16(av, bfrag[0], oacc[0][mt], 0, 0, 0);
        oacc[1][mt] = __builtin_amdgcn_mfma_f32_16x16x32_bf16(av, bfrag[1], oacc[1][mt], 0, 0, 0);
      }
    }
    __builtin_amdgcn_s_setprio(0);
  }

  // ---- epilogue: normalize, transpose O through LDS overlay, coalesced writes ----
  __syncthreads();  // all waves done with K/V/Ps before Os overlay
#pragma unroll
  for (int nt = 0; nt < 2; ++nt) {
    const float inv = l_run[nt] > 0.f ? 1.f / l_run[nt] : 1.f;
    const int qloc = wave * 32 + nt * 16 + col;
#pragma unroll
    for (int mt = 0; mt < 4; ++mt) {
      float4 w = make_float4(oacc[nt][mt][0] * inv, oacc[nt][mt][1] * inv,
                             oacc[nt][mt][2] * inv, oacc[nt][mt][3] * inv);
      *(float4*)(Os + qloc * OPAD + mt * 16 + quad * 4) = w;
    }
  }
  __syncthreads();
  float* ob = o_out + ((size_t)(b * N_ + qb128 * BLK_)) * DM_ + h * DK_;
#pragma unroll
  for (int j = 0; j < 8; ++j) {
    const int i = t + 256 * j;
    const int r = i >> 4, c4 = (i & 15) * 4;
    const float4 w = *(const float4*)(Os + r * OPAD + c4);
    *(float4*)(ob + (size_t)r * DM_ + c4) = w;
  }
  if (quad == 0) {
#pragma unroll
    for (int nt = 0; nt < 2; ++nt) {
      const size_t oi = (size_t)(b * H_ + h) * N_ + qg[nt];
      const float lv = l_run[nt] > 0.f
          ? l_run[nt] * __builtin_amdgcn_exp2f(m_run[nt] - m_true[nt]) : 0.f;
      l_out[oi] = lv;
      m_out[oi] = l_run[nt] > 0.f ? m_true[nt] * 0.69314718056f : -INFINITY;
    }
  }
}

extern "C" void kernel_launch(void* const* d_in, const int* in_sizes, int n_in,
                              void* d_out, int out_size, void* d_ws, size_t ws_size,
                              hipStream_t stream) {
  const float* q   = (const float*)d_in[0];
  const float* k   = (const float*)d_in[1];
  const float* v   = (const float*)d_in[2];
  const float* tau = (const float*)d_in[3];
  const int* mask  = (const int*)d_in[4];
  const int* bs    = (const int*)d_in[5];
  float* out = (float*)d_out;

  const size_t plane = (size_t)B_ * H_ * N_ * DK_;  // == B*H*TB*8192
  u16* kimg = (u16*)d_ws;
  u16* vimg = kimg + plane;
  int* flags = (int*)(vimg + plane);

  prepass_kernel<<<dim3(1024), 256, 0, stream>>>(k, v, mask, bs, kimg, vimg, flags);

  float* o_out = out;
  float* l_out = out + (size_t)B_ * N_ * DM_;
  float* m_out = l_out + (size_t)B_ * H_ * N_;
  attn_kernel<<<dim3(TB_ * 32), 256, 0, stream>>>(q, kimg, vimg, tau, mask, flags,
                                                  o_out, l_out, m_out);
}